// Round 3
// baseline (65.369 us; speedup 1.0000x reference)
//
#include <hip/hip_runtime.h>

#define T_LEN 1024
#define N_ORD 64

// Kernel A: KT2 layout: element ((t>>2)*64 + n)*4 + (t&3) = K[n][1023 - t]
// One float4 per thread, coalesced writes; reads are per-lane contiguous
// (reversed) float4 from K. 16384 threads total.
__global__ __launch_bounds__(256) void build_kt(const float* __restrict__ K,
                                                float4* __restrict__ KT2) {
    int g  = blockIdx.x * 256 + threadIdx.x;   // 0..16383
    int t4 = g >> 6;                           // t-group (4 t's per group)
    int n  = g & 63;
    const float4 kv = *(const float4*)(K + n * T_LEN + (1020 - 4 * t4));
    KT2[g] = make_float4(kv.w, kv.z, kv.y, kv.x);
}

// Kernel B: one block per row (512 blocks -> 2 blocks/CU -> 2 waves/SIMD).
// wave = t-quarter, lane = n. u reads are lane-invariant -> scalar loads
// (constant cache); KT2 reads coalesced b128; no LDS in the main loop.
__global__ __launch_bounds__(256) void hippo_last(const float* __restrict__ u,
                                                  const float4* __restrict__ KT2,
                                                  float* __restrict__ out) {
    __shared__ float red[4][64];        // [wave][n], 1 KB

    const int tid = threadIdx.x;
    const int r   = blockIdx.x;         // 512 rows
    const int w   = tid >> 6;           // t-quarter owned by this wave
    const int n   = tid & 63;

    const float4* uq = (const float4*)(u + r * T_LEN);  // wave-uniform base
    const int base = w * 64;            // t4 range [base, base+64)

    float acc_a = 0.f, acc_b = 0.f;     // 2 chains: dep-latency hidden at 2 waves/SIMD
    #pragma unroll 8
    for (int j = 0; j < 64; j += 2) {
        const float4 k0 = KT2[(base + j) * 64 + n];       // coalesced 1 KB/instr
        const float4 k1 = KT2[(base + j + 1) * 64 + n];
        const float4 ua = uq[base + j];                   // scalar (uniform) loads
        const float4 ub = uq[base + j + 1];
        acc_a += ua.x * k0.x + ua.y * k0.y + ua.z * k0.z + ua.w * k0.w;
        acc_b += ub.x * k1.x + ub.y * k1.y + ub.z * k1.z + ub.w * k1.w;
    }

    red[w][n] = acc_a + acc_b;
    __syncthreads();

    if (tid < 64) {                     // 256 B coalesced store
        out[r * 64 + tid] = red[0][tid] + red[1][tid] + red[2][tid] + red[3][tid];
    }
}

extern "C" void kernel_launch(void* const* d_in, const int* in_sizes, int n_in,
                              void* d_out, int out_size, void* d_ws, size_t ws_size,
                              hipStream_t stream) {
    const float* inputs = (const float*)d_in[0];   // (4,2,64,1024) fp32
    const float* K      = (const float*)d_in[1];   // (64,1024) fp32
    float* out  = (float*)d_out;                   // (4,2,64,64) fp32
    float4* KT2 = (float4*)d_ws;                   // 256 KB scratch

    build_kt<<<64, 256, 0, stream>>>(K, KT2);
    hippo_last<<<512, 256, 0, stream>>>(inputs, KT2, out);
}

// Round 4
// 65.127 us; speedup vs baseline: 1.0037x; 1.0037x over previous
//
#include <hip/hip_runtime.h>

#define T_LEN 1024

// Fused single kernel. out[r][n] = sum_s u[r][1023-s] * K[n][s].
// Layout: lane = t-direction (s = 256k + 4*lane + c), so BOTH u and K reads
// are coalesced 1KB/instr — no transpose kernel, no d_ws, no staging.
// Block = 2 rows, 256 blocks = 1/CU. Waves split n-space (16 n's each).
// u: 8 float4/lane in registers (reversed via component swap, loaded once).
// K: 256 KB total, L2-resident; 64 K-loads/lane, 32 indep FMA chains (ILP).
// Reduce: LDS stride-65 pad -> (lane + const)%32 banks = 2-way = free.
__global__ __launch_bounds__(256) void hippo_fused(const float* __restrict__ u,
                                                   const float* __restrict__ K,
                                                   float* __restrict__ out) {
    __shared__ float red[128 * 65];   // 33.3 KB

    const int tid   = threadIdx.x;
    const int rows0 = blockIdx.x * 2;     // 256 blocks x 2 rows = 512 rows
    const int w     = tid >> 6;           // wave 0..3
    const int l     = tid & 63;           // lane
    const int n0    = w * 16;             // this wave's n range

    // reversed-u fragments: ua[r][k] = u[row][1020-256k-4l .. +3]
    // lane stride -16B: same cache segments as forward -> coalesced.
    float4 ua[2][4];
    #pragma unroll
    for (int r = 0; r < 2; ++r) {
        const float* urow = u + (rows0 + r) * T_LEN;
        #pragma unroll
        for (int k = 0; k < 4; ++k)
            ua[r][k] = *(const float4*)(urow + (1020 - 256 * k - 4 * l));
    }

    float acc[2][16];
    #pragma unroll
    for (int r = 0; r < 2; ++r)
        #pragma unroll
        for (int i = 0; i < 16; ++i) acc[r][i] = 0.f;

    const float4* K4 = (const float4*)K;  // row n = 256 float4
    #pragma unroll 4
    for (int i = 0; i < 16; ++i) {
        const int n = n0 + i;
        #pragma unroll
        for (int k = 0; k < 4; ++k) {
            const float4 kv = K4[n * 256 + k * 64 + l];   // coalesced, L2-hit
            // s-offset c maps to u component d = 3-c (reversal)
            #pragma unroll
            for (int r = 0; r < 2; ++r) {
                const float4 uv = ua[r][k];
                acc[r][i] += kv.x * uv.w + kv.y * uv.z + kv.z * uv.y + kv.w * uv.x;
            }
        }
    }

    // cross-lane reduction via padded LDS
    #pragma unroll
    for (int r = 0; r < 2; ++r)
        #pragma unroll
        for (int i = 0; i < 16; ++i)
            red[(r * 64 + n0 + i) * 65 + l] = acc[r][i];
    __syncthreads();

    if (tid < 128) {                       // tid = r*64 + n
        float s = 0.f;
        const float* p = &red[tid * 65];
        #pragma unroll 8
        for (int j = 0; j < 64; ++j) s += p[j];
        out[rows0 * 64 + tid] = s;         // 512 B contiguous store
    }
}

extern "C" void kernel_launch(void* const* d_in, const int* in_sizes, int n_in,
                              void* d_out, int out_size, void* d_ws, size_t ws_size,
                              hipStream_t stream) {
    const float* inputs = (const float*)d_in[0];   // (4,2,64,1024) fp32
    const float* K      = (const float*)d_in[1];   // (64,1024) fp32
    float* out = (float*)d_out;                    // (4,2,64,64) fp32

    hippo_fused<<<256, 256, 0, stream>>>(inputs, K, out);
}

// Round 5
// 61.384 us; speedup vs baseline: 1.0649x; 1.0610x over previous
//
#include <hip/hip_runtime.h>

#define T_LEN 1024

// Fused single kernel. out[r][n] = sum_s u[r][1023-s] * K[n][s].
// lane = t-direction (s = 256k + 4*lane + c): both u and K coalesced 1KB/instr.
// 256 blocks (1/CU) x 512 threads (8 waves/CU = 2 waves/SIMD for TA latency
// hiding). Block = 2 rows; wave w covers n in [8w, 8w+8): 32 K b128 loads and
// 16 independent FMA chains per lane. K L2 traffic = 256 blocks x 256 KB =
// 64 MB -> 256 TA instrs/CU ~ 1.7 us structural floor.
__global__ __launch_bounds__(512) void hippo_fused(const float* __restrict__ u,
                                                   const float* __restrict__ K,
                                                   float* __restrict__ out) {
    __shared__ float red[128 * 65];   // 33.3 KB, +1 pad -> conflict-free tail

    const int tid   = threadIdx.x;
    const int rows0 = blockIdx.x * 2;     // 256 blocks x 2 rows = 512 rows
    const int w     = tid >> 6;           // wave 0..7
    const int l     = tid & 63;           // lane
    const int n0    = w * 8;              // this wave's n range

    // reversed-u fragments: ua[r][k] = u[row][1020-256k-4l .. +3]
    float4 ua[2][4];
    #pragma unroll
    for (int r = 0; r < 2; ++r) {
        const float* urow = u + (rows0 + r) * T_LEN;
        #pragma unroll
        for (int k = 0; k < 4; ++k)
            ua[r][k] = *(const float4*)(urow + (1020 - 256 * k - 4 * l));
    }

    float acc[2][8];
    #pragma unroll
    for (int r = 0; r < 2; ++r)
        #pragma unroll
        for (int i = 0; i < 8; ++i) acc[r][i] = 0.f;

    const float4* K4 = (const float4*)K;  // row n = 256 float4
    #pragma unroll 2
    for (int i = 0; i < 8; ++i) {
        const int n = n0 + i;
        #pragma unroll
        for (int k = 0; k < 4; ++k) {
            const float4 kv = K4[n * 256 + k * 64 + l];   // coalesced, L2-hit
            #pragma unroll
            for (int r = 0; r < 2; ++r) {                 // reversal: c -> 3-c
                const float4 uv = ua[r][k];
                acc[r][i] += kv.x * uv.w + kv.y * uv.z + kv.z * uv.y + kv.w * uv.x;
            }
        }
    }

    // cross-lane reduction via padded LDS
    #pragma unroll
    for (int r = 0; r < 2; ++r)
        #pragma unroll
        for (int i = 0; i < 8; ++i)
            red[(r * 64 + n0 + i) * 65 + l] = acc[r][i];
    __syncthreads();

    if (tid < 128) {                       // tid = r*64 + n
        float s = 0.f;
        const float* p = &red[tid * 65];
        #pragma unroll 8
        for (int j = 0; j < 64; ++j) s += p[j];
        out[rows0 * 64 + tid] = s;         // 512 B contiguous store
    }
}

extern "C" void kernel_launch(void* const* d_in, const int* in_sizes, int n_in,
                              void* d_out, int out_size, void* d_ws, size_t ws_size,
                              hipStream_t stream) {
    const float* inputs = (const float*)d_in[0];   // (4,2,64,1024) fp32
    const float* K      = (const float*)d_in[1];   // (64,1024) fp32
    float* out = (float*)d_out;                    // (4,2,64,64) fp32

    hippo_fused<<<256, 512, 0, stream>>>(inputs, K, out);
}